// Round 6
// baseline (282.159 us; speedup 1.0000x reference)
//
#include <hip/hip_runtime.h>
#include <cstdint>

#define DEV static __device__ __forceinline__

typedef __attribute__((ext_vector_type(8))) short bf16x8;   // 8 bf16 = 4 VGPRs
typedef __attribute__((ext_vector_type(4))) short bf16x4v;  // 4 bf16
typedef __attribute__((ext_vector_type(4))) float f32x4;
typedef __attribute__((ext_vector_type(4))) unsigned u32x4;

DEV float bf2f(short s) {
  union { unsigned u; float f; } c; c.u = ((unsigned)(unsigned short)s) << 16; return c.f;
}
DEV short f2bf(float f) {  // round-to-nearest-even
  union { float f; unsigned u; } c; c.f = f;
  unsigned r = c.u + 0x7FFF + ((c.u >> 16) & 1);
  return (short)(r >> 16);
}
// pack 2 f32 -> 2 bf16 in one u32 (lo = first arg), RNE. No builtin on gfx950.
DEV unsigned cvtpk(float lo, float hi) {
  unsigned r;
  asm("v_cvt_pk_bf16_f32 %0, %1, %2" : "=v"(r) : "v"(lo), "v"(hi));
  return r;
}
// async global->LDS DMA, 16B per lane (m97 pattern).
DEV void g2lds16(const void* g, void* l) {
  __builtin_amdgcn_global_load_lds(
      (const __attribute__((address_space(1))) void*)g,
      (__attribute__((address_space(3))) void*)l, 16, 0, 0);
}

// ---------------- prep: f32->bf16 convert + weight transpose, one launch ----
__global__ __launch_bounds__(256) void prep_kernel(
    const float* __restrict__ s1, short* __restrict__ s1b,
    const float* __restrict__ s2, short* __restrict__ s2b,
    const float* __restrict__ w0, short* __restrict__ t0,
    const float* __restrict__ w1, short* __restrict__ t1,
    const float* __restrict__ w2, short* __restrict__ t2,
    const float* __restrict__ w3, short* __restrict__ t3) {
  __shared__ float tile[32][33];
  const int bid = blockIdx.x, tid = threadIdx.x;
  if (bid < 8192) {
    int i = bid * 256 + tid;
    const float* in = s1; short* out = s1b;
    if (i >= 1048576) { i -= 1048576; in = s2; out = s2b; }
    float4 v = reinterpret_cast<const float4*>(in)[i];
    bf16x4v o; o[0] = f2bf(v.x); o[1] = f2bf(v.y); o[2] = f2bf(v.z); o[3] = f2bf(v.w);
    reinterpret_cast<bf16x4v*>(out)[i] = o;
  } else {
    int b2 = bid - 8192;
    int z = b2 >> 10, rem = b2 & 1023;
    int bx = rem & 31, by = rem >> 5;
    int tx = tid & 31, ty = tid >> 5;           // 32 x 8
    const float* W; short* Wt;
    switch (z) {
      case 0: W = w0; Wt = t0; break;
      case 1: W = w1; Wt = t1; break;
      case 2: W = w2; Wt = t2; break;
      default: W = w3; Wt = t3; break;
    }
#pragma unroll
    for (int j = 0; j < 4; ++j)
      tile[ty + 8 * j][tx] = W[(size_t)(by * 32 + ty + 8 * j) * 1024 + bx * 32 + tx];
    __syncthreads();
#pragma unroll
    for (int j = 0; j < 4; ++j)
      Wt[(size_t)(bx * 32 + ty + 8 * j) * 1024 + by * 32 + tx] = f2bf(tile[tx][ty + 8 * j]);
  }
}

// ---------------- shared GEMM core: m97-verified 128x128x64 structure -------
template <typename EPI>
DEV void gemm_core128(const short* __restrict__ A, const short* __restrict__ Bt,
                      int m0, int n0, EPI epi) {
  __shared__ alignas(16) short As[128 * 64];   // [m-local][k] linear (g2lds dest)
  __shared__ alignas(16) short Bs[128 * 64];   // [n-local][k] linear
  const int tid = threadIdx.x, lane = tid & 63, w = tid >> 6;
  const int wm = (w >> 1) * 64, wn = (w & 1) * 64;

  f32x4 acc[4][4] = {};

  for (int kt = 0; kt < 16; ++kt) {
    __syncthreads();   // prev iter's frag reads done
#pragma unroll
    for (int rnd = 0; rnd < 4; ++rnd) {      // A: 128 rows x 64 k
      int c = tid + rnd * 256;
      int row = c >> 3, ch = c & 7;
      g2lds16(A + (size_t)(m0 + row) * 1024 + kt * 64 + ch * 8, (char*)As + c * 16);
    }
#pragma unroll
    for (int rnd = 0; rnd < 4; ++rnd) {      // B: 128 rows x 64 k
      int c = tid + rnd * 256;
      int row = c >> 3, ch = c & 7;
      g2lds16(Bt + (size_t)(n0 + row) * 1024 + kt * 64 + ch * 8, (char*)Bs + c * 16);
    }
    asm volatile("s_waitcnt vmcnt(0)" ::: "memory");
    __syncthreads();
#pragma unroll
    for (int kk = 0; kk < 64; kk += 32) {
      bf16x8 a[4], b[4];
#pragma unroll
      for (int i = 0; i < 4; ++i)
        a[i] = *reinterpret_cast<const bf16x8*>(&As[(wm + i * 16 + (lane & 15)) * 64 + kk + 8 * (lane >> 4)]);
#pragma unroll
      for (int i = 0; i < 4; ++i)
        b[i] = *reinterpret_cast<const bf16x8*>(&Bs[(wn + i * 16 + (lane & 15)) * 64 + kk + 8 * (lane >> 4)]);
#pragma unroll
      for (int mi = 0; mi < 4; ++mi)
#pragma unroll
        for (int ni = 0; ni < 4; ++ni)
          acc[mi][ni] = __builtin_amdgcn_mfma_f32_16x16x32_bf16(a[mi], b[ni], acc[mi][ni], 0, 0, 0);
    }
  }
  // D layout (m89-verified): row = 4*(lane>>4)+r, col = lane&15
#pragma unroll
  for (int mi = 0; mi < 4; ++mi)
#pragma unroll
    for (int ni = 0; ni < 4; ++ni)
#pragma unroll
      for (int r = 0; r < 4; ++r) {
        int m = m0 + wm + mi * 16 + 4 * (lane >> 4) + r;
        int n = n0 + wn + ni * 16 + (lane & 15);
        epi(m, n, acc[mi][ni][r]);
      }
}

// merged Q/K/V projections (see R4 notes). XCD-swizzled.
__global__ __launch_bounds__(256) void qkv_gemm_kernel(
    const short* __restrict__ s1b, const short* __restrict__ s2b,
    const short* __restrict__ wqt, const short* __restrict__ wkt,
    const short* __restrict__ wvt,
    const float* __restrict__ bq, const float* __restrict__ bk,
    const float* __restrict__ bv,
    short* __restrict__ qb, short* __restrict__ kb, short* __restrict__ vtb) {
  const int z = blockIdx.z;
  int flat = blockIdx.y * 8 + blockIdx.x;       // 256 blocks/slice, %8==0
  int r8 = flat & 7, q8 = flat >> 3;
  int lg = r8 * 32 + q8;                        // XCD r8 gets lg in [32*r8, 32*r8+32)
  if (z < 2) {
    const short* A = (z == 0) ? s1b : s2b;
    const short* Bt = (z == 0) ? wqt : wkt;
    const float* bias = (z == 0) ? bq : bk;
    short* out = (z == 0) ? qb : kb;
    int n0 = (lg & 7) * 128, m0 = (lg >> 3) * 128;  // m over 4096 (seq), n over 1024
    gemm_core128(A, Bt, m0, n0, [&](int m, int n, float v) {
      v += bias[n];  // n = feature dim
      out[(((size_t)(m >> 9) * 16 + (n >> 6)) * 512 + (m & 511)) * 64 + (n & 63)] = f2bf(v);
    });
  } else {
    int m0 = (lg & 7) * 128, n0 = (lg >> 3) * 128;  // m over 1024 (d), n over 4096 (s)
    gemm_core128(wvt, s2b, m0, n0, [&](int m, int n, float v) {
      v += bv[m];    // m = feature dim (d)
      vtb[(((size_t)(n >> 9) * 16 + (m >> 6)) * 64 + (m & 63)) * 512 + (n & 511)] = f2bf(v);
    });
  }
}

// Wo projection + bias + s1 residual, f32 row-major output
__global__ __launch_bounds__(256) void wo_gemm_kernel(
    const short* __restrict__ A, const short* __restrict__ Bt,
    const float* __restrict__ bias, const float* __restrict__ s1,
    float* __restrict__ out) {
  int flat = blockIdx.y * 8 + blockIdx.x;       // 256 blocks
  int r8 = flat & 7, q8 = flat >> 3;
  int lg = r8 * 32 + q8;
  int n0 = (lg & 7) * 128, m0 = (lg >> 3) * 128;
  gemm_core128(A, Bt, m0, n0, [&](int m, int n, float v) {
    out[(size_t)m * 1024 + n] = v + bias[n] + s1[(size_t)m * 1024 + n];
  });
}

// ---------------- fused attention: fully register-resident ------------------
// ZERO LDS, ZERO barriers. Wave-independent: each wave owns 16 q-rows
// (q = l15 for all its lanes). Scores/P live in 64 packed-bf16 VGPRs per
// lane, in PV-ready layout: P[4m+j] = bf16x2 of k = 32m + 8*l4 + 2j + {0,1}.
// Layout achieved by a per-score-tile 4-lane-group exchange (shfl_xor 16/32).
// __launch_bounds__(256,4): cap 128 VGPR -> 4 waves/SIMD (2x the LDS design).
__global__ __launch_bounds__(256, 4) void attn_kernel(
    const short* __restrict__ Qg, const short* __restrict__ Kg,
    const short* __restrict__ Vtg, const float* __restrict__ maskg,
    const int* __restrict__ clp, short* __restrict__ ctx) {
  const int tid = threadIdx.x, lane = tid & 63, w = tid >> 6;
  const int l15 = lane & 15, l4 = lane >> 4;
  int flat = blockIdx.y * 8 + blockIdx.x;     // 1024 blocks
  int r8 = flat & 7, q8 = flat >> 3;
  int lg = r8 * 128 + q8;                     // XCD r8: bh in [16*r8, 16*r8+16)
  const int qt = lg & 7, bh = lg >> 3, b = bh >> 4;
  const int cl = clp[0];
  const float* mrow = maskg + b * 512;

  // Q fragments straight to registers ([bh][s][64] row-major)
  const short* qbase = Qg + ((size_t)bh * 512 + qt * 64 + w * 16 + l15) * 64 + 8 * l4;
  bf16x8 qf0 = *reinterpret_cast<const bf16x8*>(qbase);
  bf16x8 qf1 = *reinterpret_cast<const bf16x8*>(qbase + 32);

  unsigned P[64];          // packed bf16 scores/probs, PV-ready layout
  float m1 = -1e30f;
  const short* kbh = Kg + (size_t)bh * 512 * 64 + 8 * l4;
  const bool odd = (l4 & 1);

  // phase 1: S = K Q^T / 8 + mask (swapped operands), exchange into P
#pragma unroll
  for (int kt = 0; kt < 8; ++kt) {
#pragma unroll
    for (int ni = 0; ni < 4; ++ni) {
      const short* kp = kbh + (size_t)(kt * 64 + ni * 16 + l15) * 64;
      bf16x8 k0 = *reinterpret_cast<const bf16x8*>(kp);
      bf16x8 k1 = *reinterpret_cast<const bf16x8*>(kp + 32);
      f32x4 acc = {};
      acc = __builtin_amdgcn_mfma_f32_16x16x32_bf16(k0, qf0, acc, 0, 0, 0);
      acc = __builtin_amdgcn_mfma_f32_16x16x32_bf16(k1, qf1, acc, 0, 0, 0);
      // C layout: lane holds k = kt*64+ni*16+4*l4+{0..3} for q-row l15
      f32x4 mk = *reinterpret_cast<const f32x4*>(&mrow[kt * 64 + ni * 16 + 4 * l4]);
      float s0 = fmaf(acc[0], 0.125f, mk[0]);
      float s1v = fmaf(acc[1], 0.125f, mk[1]);
      float s2v = fmaf(acc[2], 0.125f, mk[2]);
      float s3 = fmaf(acc[3], 0.125f, mk[3]);
      m1 = fmaxf(m1, fmaxf(fmaxf(s0, s1v), fmaxf(s2v, s3)));
      unsigned pk0 = cvtpk(s0, s1v), pk1 = cvtpk(s2v, s3);
      // exchange into PV layout: pair-swap across l4^1, then group-copy l4^2.
      unsigned e0 = __shfl_xor(pk0, 16), e1 = __shfl_xor(pk1, 16);
      // ascending half of this tile held by this group (lanes of l4>>1):
      unsigned h0 = odd ? e0 : pk0;
      unsigned h1 = odd ? e1 : pk1;
      unsigned h2 = odd ? pk0 : e0;
      unsigned h3 = odd ? pk1 : e1;
      unsigned g0 = __shfl_xor(h0, 32), g1 = __shfl_xor(h1, 32);
      unsigned g2 = __shfl_xor(h2, 32), g3 = __shfl_xor(h3, 32);
      bool ist = (((l4 >> 1) & 1) == (ni & 1));   // this tile feeds my k-range
      bool useh = ((l4 & 1) == (ni & 1));         // my half is in my own group
      unsigned w0 = useh ? h0 : g0;
      unsigned w1 = useh ? h1 : g1;
      unsigned w2 = useh ? h2 : g2;
      unsigned w3 = useh ? h3 : g3;
      const int mIdx = kt * 2 + (ni >> 1);
      P[4 * mIdx + 0] = ist ? w0 : P[4 * mIdx + 0];
      P[4 * mIdx + 1] = ist ? w1 : P[4 * mIdx + 1];
      P[4 * mIdx + 2] = ist ? w2 : P[4 * mIdx + 2];
      P[4 * mIdx + 3] = ist ? w3 : P[4 * mIdx + 3];
    }
  }

  // phase 2: double softmax on registers. 4 lanes (l4) share q-row l15.
  m1 = fmaxf(m1, __shfl_xor(m1, 16));
  m1 = fmaxf(m1, __shfl_xor(m1, 32));
  float Z1 = 0.f;
#pragma unroll
  for (int i = 0; i < 64; ++i) {
    unsigned u = P[i];
    float lo = __uint_as_float(u << 16);
    float hi = __uint_as_float(u & 0xffff0000u);
    float e0 = __expf(lo - m1), e1 = __expf(hi - m1);
    Z1 += e0 + e1;
    P[i] = cvtpk(e0, e1);
  }
  Z1 += __shfl_xor(Z1, 16); Z1 += __shfl_xor(Z1, 32);
  float rZ1 = 1.0f / Z1;
  float rowscale = rZ1;        // P holds unnormalized e; fold 1/Z into epilogue

  if (cl) {  // softmax(1 - p + mask), p = e1*rZ1
    float m2 = -1e30f;
#pragma unroll
    for (int m = 0; m < 16; ++m) {
      f32x4 mka = *reinterpret_cast<const f32x4*>(&mrow[32 * m + 8 * l4]);
      f32x4 mkb = *reinterpret_cast<const f32x4*>(&mrow[32 * m + 8 * l4 + 4]);
#pragma unroll
      for (int j = 0; j < 4; ++j) {
        unsigned u = P[4 * m + j];
        float p0 = __uint_as_float(u << 16) * rZ1;
        float p1 = __uint_as_float(u & 0xffff0000u) * rZ1;
        float mv0 = (j < 2) ? mka[2 * j] : mkb[2 * j - 4];
        float mv1 = (j < 2) ? mka[2 * j + 1] : mkb[2 * j - 3];
        m2 = fmaxf(m2, fmaxf(1.0f - p0 + mv0, 1.0f - p1 + mv1));
      }
    }
    m2 = fmaxf(m2, __shfl_xor(m2, 16));
    m2 = fmaxf(m2, __shfl_xor(m2, 32));
    float Z2 = 0.f;
#pragma unroll
    for (int m = 0; m < 16; ++m) {
      f32x4 mka = *reinterpret_cast<const f32x4*>(&mrow[32 * m + 8 * l4]);
      f32x4 mkb = *reinterpret_cast<const f32x4*>(&mrow[32 * m + 8 * l4 + 4]);
#pragma unroll
      for (int j = 0; j < 4; ++j) {
        unsigned u = P[4 * m + j];
        float p0 = __uint_as_float(u << 16) * rZ1;
        float p1 = __uint_as_float(u & 0xffff0000u) * rZ1;
        float mv0 = (j < 2) ? mka[2 * j] : mkb[2 * j - 4];
        float mv1 = (j < 2) ? mka[2 * j + 1] : mkb[2 * j - 3];
        float e0 = __expf(1.0f - p0 + mv0 - m2);
        float e1 = __expf(1.0f - p1 + mv1 - m2);
        Z2 += e0 + e1;
        P[4 * m + j] = cvtpk(e0, e1);
      }
    }
    Z2 += __shfl_xor(Z2, 16); Z2 += __shfl_xor(Z2, 32);
    rowscale = 1.0f / Z2;
  }

  // phase 3: ctx = P @ V. A-frag = P[4m..4m+3] (already PV layout), B = Vt.
  f32x4 o[4] = {};
  const short* vbh = Vtg + (size_t)bh * 64 * 512 + 8 * l4;
#pragma unroll
  for (int m = 0; m < 16; ++m) {
    u32x4 av;
    av[0] = P[4 * m + 0]; av[1] = P[4 * m + 1];
    av[2] = P[4 * m + 2]; av[3] = P[4 * m + 3];
    bf16x8 a = __builtin_bit_cast(bf16x8, av);
    bf16x8 b0 = *reinterpret_cast<const bf16x8*>(vbh + (size_t)(0 * 16 + l15) * 512 + m * 32);
    bf16x8 b1 = *reinterpret_cast<const bf16x8*>(vbh + (size_t)(1 * 16 + l15) * 512 + m * 32);
    bf16x8 b2 = *reinterpret_cast<const bf16x8*>(vbh + (size_t)(2 * 16 + l15) * 512 + m * 32);
    bf16x8 b3 = *reinterpret_cast<const bf16x8*>(vbh + (size_t)(3 * 16 + l15) * 512 + m * 32);
    __builtin_amdgcn_s_setprio(1);
    o[0] = __builtin_amdgcn_mfma_f32_16x16x32_bf16(a, b0, o[0], 0, 0, 0);
    o[1] = __builtin_amdgcn_mfma_f32_16x16x32_bf16(a, b1, o[1], 0, 0, 0);
    o[2] = __builtin_amdgcn_mfma_f32_16x16x32_bf16(a, b2, o[2], 0, 0, 0);
    o[3] = __builtin_amdgcn_mfma_f32_16x16x32_bf16(a, b3, o[3], 0, 0, 0);
    __builtin_amdgcn_s_setprio(0);
  }
  // C layout: lane holds ctx[q = 4*l4+r][d = ni*16+l15]; rowscale for q=Q
  // lives (post-reduce) in all lanes with l15==Q -> pull from lane 4*l4+r.
  float sc[4];
#pragma unroll
  for (int r = 0; r < 4; ++r) sc[r] = __shfl(rowscale, 4 * l4 + r);
  const int h = bh & 15;
#pragma unroll
  for (int ni = 0; ni < 4; ++ni)
#pragma unroll
    for (int r = 0; r < 4; ++r) {
      int s = qt * 64 + w * 16 + 4 * l4 + r;
      int d = ni * 16 + l15;
      ctx[((size_t)b * 512 + s) * 1024 + h * 64 + d] = f2bf(o[ni][r] * sc[r]);
    }
}

// ---------------- LayerNorm (input already h + bias + s1) -------------------
__global__ __launch_bounds__(256) void ln_kernel(
    const float* __restrict__ hbuf,
    const float* __restrict__ lw, const float* __restrict__ lb,
    float* __restrict__ out) {
  __shared__ float red[8];
  const int row = blockIdx.x, tid = threadIdx.x;
  float4 hv = reinterpret_cast<const float4*>(hbuf + (size_t)row * 1024)[tid];
  float x0 = hv.x, x1 = hv.y, x2 = hv.z, x3 = hv.w;
  float s = x0 + x1 + x2 + x3;
  float ss = x0 * x0 + x1 * x1 + x2 * x2 + x3 * x3;
  for (int o = 32; o; o >>= 1) { s += __shfl_down(s, o); ss += __shfl_down(ss, o); }
  int w = tid >> 6;
  if ((tid & 63) == 0) { red[w] = s; red[4 + w] = ss; }
  __syncthreads();
  float S = red[0] + red[1] + red[2] + red[3];
  float SS = red[4] + red[5] + red[6] + red[7];
  float u = S * (1.f / 1024.f);
  float var = SS * (1.f / 1024.f) - u * u;
  float inv = rsqrtf(var + 1e-12f);
  float4 wv = reinterpret_cast<const float4*>(lw)[tid];
  float4 bv = reinterpret_cast<const float4*>(lb)[tid];
  float4 ov;
  ov.x = wv.x * (x0 - u) * inv + bv.x;
  ov.y = wv.y * (x1 - u) * inv + bv.y;
  ov.z = wv.z * (x2 - u) * inv + bv.z;
  ov.w = wv.w * (x3 - u) * inv + bv.w;
  reinterpret_cast<float4*>(out + (size_t)row * 1024)[tid] = ov;
}

// ---------------- launcher ---------------------------------------------------
extern "C" void kernel_launch(void* const* d_in, const int* in_sizes, int n_in,
                              void* d_out, int out_size, void* d_ws, size_t ws_size,
                              hipStream_t stream) {
  const float* s1 = (const float*)d_in[0];
  const float* s2 = (const float*)d_in[1];
  const float* mask = (const float*)d_in[2];
  const float* Wq = (const float*)d_in[3]; const float* bq = (const float*)d_in[4];
  const float* Wk = (const float*)d_in[5]; const float* bk = (const float*)d_in[6];
  const float* Wv = (const float*)d_in[7]; const float* bv = (const float*)d_in[8];
  const float* Wo = (const float*)d_in[9]; const float* bo = (const float*)d_in[10];
  const float* lnw = (const float*)d_in[11]; const float* lnb = (const float*)d_in[12];
  const int* cl = (const int*)d_in[13];
  float* out = (float*)d_out;

  char* ws = (char*)d_ws;
  short* s1b = (short*)ws; ws += (size_t)4096 * 1024 * 2;
  short* s2b = (short*)ws; ws += (size_t)4096 * 1024 * 2;
  short* wqt = (short*)ws; ws += (size_t)1024 * 1024 * 2;
  short* wkt = (short*)ws; ws += (size_t)1024 * 1024 * 2;
  short* wvt = (short*)ws; ws += (size_t)1024 * 1024 * 2;
  short* wot = (short*)ws; ws += (size_t)1024 * 1024 * 2;
  short* qb  = (short*)ws; ws += (size_t)4096 * 1024 * 2;
  short* kb  = (short*)ws; ws += (size_t)4096 * 1024 * 2;
  short* vtb = (short*)ws; ws += (size_t)4096 * 1024 * 2;
  short* ctxb= (short*)ws; ws += (size_t)4096 * 1024 * 2;
  float* hb  = (float*)ws; ws += (size_t)4096 * 1024 * 4;

  prep_kernel<<<12288, 256, 0, stream>>>(s1, s1b, s2, s2b,
                                         Wq, wqt, Wk, wkt, Wv, wvt, Wo, wot);
  qkv_gemm_kernel<<<dim3(8, 32, 3), 256, 0, stream>>>(s1b, s2b, wqt, wkt, wvt,
                                                      bq, bk, bv, qb, kb, vtb);
  attn_kernel<<<dim3(8, 128), 256, 0, stream>>>(qb, kb, vtb, mask, cl, ctxb);
  wo_gemm_kernel<<<dim3(8, 32), 256, 0, stream>>>(ctxb, wot, bo, s1, hb);
  ln_kernel<<<4096, 256, 0, stream>>>(hb, lnw, lnb, out);
}

// Round 7
// 265.666 us; speedup vs baseline: 1.0621x; 1.0621x over previous
//
#include <hip/hip_runtime.h>
#include <cstdint>

#define DEV static __device__ __forceinline__

typedef __attribute__((ext_vector_type(8))) short bf16x8;   // 8 bf16 = 4 VGPRs
typedef __attribute__((ext_vector_type(4))) short bf16x4v;  // 4 bf16
typedef __attribute__((ext_vector_type(4))) float f32x4;
typedef __attribute__((ext_vector_type(4))) unsigned u32x4;

DEV float bf2f(short s) {
  union { unsigned u; float f; } c; c.u = ((unsigned)(unsigned short)s) << 16; return c.f;
}
DEV short f2bf(float f) {  // round-to-nearest-even
  union { float f; unsigned u; } c; c.f = f;
  unsigned r = c.u + 0x7FFF + ((c.u >> 16) & 1);
  return (short)(r >> 16);
}
// pack 2 f32 -> 2 bf16 in one u32 (lo = first arg), RNE. No builtin on gfx950.
DEV unsigned cvtpk(float lo, float hi) {
  unsigned r;
  asm("v_cvt_pk_bf16_f32 %0, %1, %2" : "=v"(r) : "v"(lo), "v"(hi));
  return r;
}
// async global->LDS DMA, 16B per lane (m97 pattern).
DEV void g2lds16(const void* g, void* l) {
  __builtin_amdgcn_global_load_lds(
      (const __attribute__((address_space(1))) void*)g,
      (__attribute__((address_space(3))) void*)l, 16, 0, 0);
}

// ---------------- prep: f32->bf16 convert + weight transpose, one launch ----
__global__ __launch_bounds__(256) void prep_kernel(
    const float* __restrict__ s1, short* __restrict__ s1b,
    const float* __restrict__ s2, short* __restrict__ s2b,
    const float* __restrict__ w0, short* __restrict__ t0,
    const float* __restrict__ w1, short* __restrict__ t1,
    const float* __restrict__ w2, short* __restrict__ t2,
    const float* __restrict__ w3, short* __restrict__ t3) {
  __shared__ float tile[32][33];
  const int bid = blockIdx.x, tid = threadIdx.x;
  if (bid < 8192) {
    int i = bid * 256 + tid;
    const float* in = s1; short* out = s1b;
    if (i >= 1048576) { i -= 1048576; in = s2; out = s2b; }
    float4 v = reinterpret_cast<const float4*>(in)[i];
    bf16x4v o; o[0] = f2bf(v.x); o[1] = f2bf(v.y); o[2] = f2bf(v.z); o[3] = f2bf(v.w);
    reinterpret_cast<bf16x4v*>(out)[i] = o;
  } else {
    int b2 = bid - 8192;
    int z = b2 >> 10, rem = b2 & 1023;
    int bx = rem & 31, by = rem >> 5;
    int tx = tid & 31, ty = tid >> 5;           // 32 x 8
    const float* W; short* Wt;
    switch (z) {
      case 0: W = w0; Wt = t0; break;
      case 1: W = w1; Wt = t1; break;
      case 2: W = w2; Wt = t2; break;
      default: W = w3; Wt = t3; break;
    }
#pragma unroll
    for (int j = 0; j < 4; ++j)
      tile[ty + 8 * j][tx] = W[(size_t)(by * 32 + ty + 8 * j) * 1024 + bx * 32 + tx];
    __syncthreads();
#pragma unroll
    for (int j = 0; j < 4; ++j)
      Wt[(size_t)(bx * 32 + ty + 8 * j) * 1024 + by * 32 + tx] = f2bf(tile[tx][ty + 8 * j]);
  }
}

// ---------------- shared GEMM core: m97-verified 128x128x64 structure -------
template <typename EPI>
DEV void gemm_core128(const short* __restrict__ A, const short* __restrict__ Bt,
                      int m0, int n0, EPI epi) {
  __shared__ alignas(16) short As[128 * 64];   // [m-local][k] linear (g2lds dest)
  __shared__ alignas(16) short Bs[128 * 64];   // [n-local][k] linear
  const int tid = threadIdx.x, lane = tid & 63, w = tid >> 6;
  const int wm = (w >> 1) * 64, wn = (w & 1) * 64;

  f32x4 acc[4][4] = {};

  for (int kt = 0; kt < 16; ++kt) {
    __syncthreads();   // prev iter's frag reads done
#pragma unroll
    for (int rnd = 0; rnd < 4; ++rnd) {      // A: 128 rows x 64 k
      int c = tid + rnd * 256;
      int row = c >> 3, ch = c & 7;
      g2lds16(A + (size_t)(m0 + row) * 1024 + kt * 64 + ch * 8, (char*)As + c * 16);
    }
#pragma unroll
    for (int rnd = 0; rnd < 4; ++rnd) {      // B: 128 rows x 64 k
      int c = tid + rnd * 256;
      int row = c >> 3, ch = c & 7;
      g2lds16(Bt + (size_t)(n0 + row) * 1024 + kt * 64 + ch * 8, (char*)Bs + c * 16);
    }
    asm volatile("s_waitcnt vmcnt(0)" ::: "memory");
    __syncthreads();
#pragma unroll
    for (int kk = 0; kk < 64; kk += 32) {
      bf16x8 a[4], b[4];
#pragma unroll
      for (int i = 0; i < 4; ++i)
        a[i] = *reinterpret_cast<const bf16x8*>(&As[(wm + i * 16 + (lane & 15)) * 64 + kk + 8 * (lane >> 4)]);
#pragma unroll
      for (int i = 0; i < 4; ++i)
        b[i] = *reinterpret_cast<const bf16x8*>(&Bs[(wn + i * 16 + (lane & 15)) * 64 + kk + 8 * (lane >> 4)]);
#pragma unroll
      for (int mi = 0; mi < 4; ++mi)
#pragma unroll
        for (int ni = 0; ni < 4; ++ni)
          acc[mi][ni] = __builtin_amdgcn_mfma_f32_16x16x32_bf16(a[mi], b[ni], acc[mi][ni], 0, 0, 0);
    }
  }
  // D layout (m89-verified): row = 4*(lane>>4)+r, col = lane&15
#pragma unroll
  for (int mi = 0; mi < 4; ++mi)
#pragma unroll
    for (int ni = 0; ni < 4; ++ni)
#pragma unroll
      for (int r = 0; r < 4; ++r) {
        int m = m0 + wm + mi * 16 + 4 * (lane >> 4) + r;
        int n = n0 + wn + ni * 16 + (lane & 15);
        epi(m, n, acc[mi][ni][r]);
      }
}

// merged Q/K/V projections (see R4 notes). XCD-swizzled.
__global__ __launch_bounds__(256) void qkv_gemm_kernel(
    const short* __restrict__ s1b, const short* __restrict__ s2b,
    const short* __restrict__ wqt, const short* __restrict__ wkt,
    const short* __restrict__ wvt,
    const float* __restrict__ bq, const float* __restrict__ bk,
    const float* __restrict__ bv,
    short* __restrict__ qb, short* __restrict__ kb, short* __restrict__ vtb) {
  const int z = blockIdx.z;
  int flat = blockIdx.y * 8 + blockIdx.x;       // 256 blocks/slice, %8==0
  int r8 = flat & 7, q8 = flat >> 3;
  int lg = r8 * 32 + q8;                        // XCD r8 gets lg in [32*r8, 32*r8+32)
  if (z < 2) {
    const short* A = (z == 0) ? s1b : s2b;
    const short* Bt = (z == 0) ? wqt : wkt;
    const float* bias = (z == 0) ? bq : bk;
    short* out = (z == 0) ? qb : kb;
    int n0 = (lg & 7) * 128, m0 = (lg >> 3) * 128;  // m over 4096 (seq), n over 1024
    gemm_core128(A, Bt, m0, n0, [&](int m, int n, float v) {
      v += bias[n];  // n = feature dim
      out[(((size_t)(m >> 9) * 16 + (n >> 6)) * 512 + (m & 511)) * 64 + (n & 63)] = f2bf(v);
    });
  } else {
    int m0 = (lg & 7) * 128, n0 = (lg >> 3) * 128;  // m over 1024 (d), n over 4096 (s)
    gemm_core128(wvt, s2b, m0, n0, [&](int m, int n, float v) {
      v += bv[m];    // m = feature dim (d)
      vtb[(((size_t)(n >> 9) * 16 + (m >> 6)) * 64 + (m & 63)) * 512 + (n & 511)] = f2bf(v);
    });
  }
}

// Wo projection + bias + s1 residual, f32 row-major output
__global__ __launch_bounds__(256) void wo_gemm_kernel(
    const short* __restrict__ A, const short* __restrict__ Bt,
    const float* __restrict__ bias, const float* __restrict__ s1,
    float* __restrict__ out) {
  int flat = blockIdx.y * 8 + blockIdx.x;       // 256 blocks
  int r8 = flat & 7, q8 = flat >> 3;
  int lg = r8 * 32 + q8;
  int n0 = (lg & 7) * 128, m0 = (lg >> 3) * 128;
  gemm_core128(A, Bt, m0, n0, [&](int m, int n, float v) {
    out[(size_t)m * 1024 + n] = v + bias[n] + s1[(size_t)m * 1024 + n];
  });
}

// ---------------- fused attention: fully register-resident ------------------
// ZERO LDS, ZERO barriers. Wave-independent: each wave owns 16 q-rows
// (q = l15 for all its lanes). Scores/P live in 64 packed-bf16 VGPRs per
// lane, in PV-ready layout: P[4m+j] = bf16x2 of k = 32m + 8*l4 + 2j + {0,1}.
// Layout achieved by a per-score-tile 4-lane-group exchange (shfl_xor 16/32).
// __launch_bounds__(256, 2): R6's (256,4) capped the unified VGPR file at 128
// and (after the arch/AGPR split) left ~64 arch regs -> P[64] spilled to
// scratch (92 MB/dispatch scratch writes, kernel 100% spill-BW-bound).
// 256-reg cap lets P live in registers; occupancy settles ~3 waves/SIMD.
__global__ __launch_bounds__(256, 2) void attn_kernel(
    const short* __restrict__ Qg, const short* __restrict__ Kg,
    const short* __restrict__ Vtg, const float* __restrict__ maskg,
    const int* __restrict__ clp, short* __restrict__ ctx) {
  const int tid = threadIdx.x, lane = tid & 63, w = tid >> 6;
  const int l15 = lane & 15, l4 = lane >> 4;
  int flat = blockIdx.y * 8 + blockIdx.x;     // 1024 blocks
  int r8 = flat & 7, q8 = flat >> 3;
  int lg = r8 * 128 + q8;                     // XCD r8: bh in [16*r8, 16*r8+16)
  const int qt = lg & 7, bh = lg >> 3, b = bh >> 4;
  const int cl = clp[0];
  const float* mrow = maskg + b * 512;

  // Q fragments straight to registers ([bh][s][64] row-major)
  const short* qbase = Qg + ((size_t)bh * 512 + qt * 64 + w * 16 + l15) * 64 + 8 * l4;
  bf16x8 qf0 = *reinterpret_cast<const bf16x8*>(qbase);
  bf16x8 qf1 = *reinterpret_cast<const bf16x8*>(qbase + 32);

  unsigned P[64];          // packed bf16 scores/probs, PV-ready layout
  float m1 = -1e30f;
  const short* kbh = Kg + (size_t)bh * 512 * 64 + 8 * l4;
  const bool odd = (l4 & 1);

  // phase 1: S = K Q^T / 8 + mask (swapped operands), exchange into P
#pragma unroll
  for (int kt = 0; kt < 8; ++kt) {
#pragma unroll
    for (int ni = 0; ni < 4; ++ni) {
      const short* kp = kbh + (size_t)(kt * 64 + ni * 16 + l15) * 64;
      bf16x8 k0 = *reinterpret_cast<const bf16x8*>(kp);
      bf16x8 k1 = *reinterpret_cast<const bf16x8*>(kp + 32);
      f32x4 acc = {};
      acc = __builtin_amdgcn_mfma_f32_16x16x32_bf16(k0, qf0, acc, 0, 0, 0);
      acc = __builtin_amdgcn_mfma_f32_16x16x32_bf16(k1, qf1, acc, 0, 0, 0);
      // C layout: lane holds k = kt*64+ni*16+4*l4+{0..3} for q-row l15
      f32x4 mk = *reinterpret_cast<const f32x4*>(&mrow[kt * 64 + ni * 16 + 4 * l4]);
      float s0 = fmaf(acc[0], 0.125f, mk[0]);
      float s1v = fmaf(acc[1], 0.125f, mk[1]);
      float s2v = fmaf(acc[2], 0.125f, mk[2]);
      float s3 = fmaf(acc[3], 0.125f, mk[3]);
      m1 = fmaxf(m1, fmaxf(fmaxf(s0, s1v), fmaxf(s2v, s3)));
      unsigned pk0 = cvtpk(s0, s1v), pk1 = cvtpk(s2v, s3);
      // exchange into PV layout: pair-swap across l4^1, then group-copy l4^2.
      unsigned e0 = __shfl_xor(pk0, 16), e1 = __shfl_xor(pk1, 16);
      // ascending half of this tile held by this group (lanes of l4>>1):
      unsigned h0 = odd ? e0 : pk0;
      unsigned h1 = odd ? e1 : pk1;
      unsigned h2 = odd ? pk0 : e0;
      unsigned h3 = odd ? pk1 : e1;
      unsigned g0 = __shfl_xor(h0, 32), g1 = __shfl_xor(h1, 32);
      unsigned g2 = __shfl_xor(h2, 32), g3 = __shfl_xor(h3, 32);
      bool ist = (((l4 >> 1) & 1) == (ni & 1));   // this tile feeds my k-range
      bool useh = ((l4 & 1) == (ni & 1));         // my half is in my own group
      unsigned w0 = useh ? h0 : g0;
      unsigned w1 = useh ? h1 : g1;
      unsigned w2 = useh ? h2 : g2;
      unsigned w3 = useh ? h3 : g3;
      const int mIdx = kt * 2 + (ni >> 1);
      P[4 * mIdx + 0] = ist ? w0 : P[4 * mIdx + 0];
      P[4 * mIdx + 1] = ist ? w1 : P[4 * mIdx + 1];
      P[4 * mIdx + 2] = ist ? w2 : P[4 * mIdx + 2];
      P[4 * mIdx + 3] = ist ? w3 : P[4 * mIdx + 3];
    }
  }

  // phase 2: double softmax on registers. 4 lanes (l4) share q-row l15.
  m1 = fmaxf(m1, __shfl_xor(m1, 16));
  m1 = fmaxf(m1, __shfl_xor(m1, 32));
  float Z1 = 0.f;
#pragma unroll
  for (int i = 0; i < 64; ++i) {
    unsigned u = P[i];
    float lo = __uint_as_float(u << 16);
    float hi = __uint_as_float(u & 0xffff0000u);
    float e0 = __expf(lo - m1), e1 = __expf(hi - m1);
    Z1 += e0 + e1;
    P[i] = cvtpk(e0, e1);
  }
  Z1 += __shfl_xor(Z1, 16); Z1 += __shfl_xor(Z1, 32);
  float rZ1 = 1.0f / Z1;
  float rowscale = rZ1;        // P holds unnormalized e; fold 1/Z into epilogue

  if (cl) {  // softmax(1 - p + mask), p = e1*rZ1
    float m2 = -1e30f;
#pragma unroll
    for (int m = 0; m < 16; ++m) {
      f32x4 mka = *reinterpret_cast<const f32x4*>(&mrow[32 * m + 8 * l4]);
      f32x4 mkb = *reinterpret_cast<const f32x4*>(&mrow[32 * m + 8 * l4 + 4]);
#pragma unroll
      for (int j = 0; j < 4; ++j) {
        unsigned u = P[4 * m + j];
        float p0 = __uint_as_float(u << 16) * rZ1;
        float p1 = __uint_as_float(u & 0xffff0000u) * rZ1;
        float mv0 = (j < 2) ? mka[2 * j] : mkb[2 * j - 4];
        float mv1 = (j < 2) ? mka[2 * j + 1] : mkb[2 * j - 3];
        m2 = fmaxf(m2, fmaxf(1.0f - p0 + mv0, 1.0f - p1 + mv1));
      }
    }
    m2 = fmaxf(m2, __shfl_xor(m2, 16));
    m2 = fmaxf(m2, __shfl_xor(m2, 32));
    float Z2 = 0.f;
#pragma unroll
    for (int m = 0; m < 16; ++m) {
      f32x4 mka = *reinterpret_cast<const f32x4*>(&mrow[32 * m + 8 * l4]);
      f32x4 mkb = *reinterpret_cast<const f32x4*>(&mrow[32 * m + 8 * l4 + 4]);
#pragma unroll
      for (int j = 0; j < 4; ++j) {
        unsigned u = P[4 * m + j];
        float p0 = __uint_as_float(u << 16) * rZ1;
        float p1 = __uint_as_float(u & 0xffff0000u) * rZ1;
        float mv0 = (j < 2) ? mka[2 * j] : mkb[2 * j - 4];
        float mv1 = (j < 2) ? mka[2 * j + 1] : mkb[2 * j - 3];
        float e0 = __expf(1.0f - p0 + mv0 - m2);
        float e1 = __expf(1.0f - p1 + mv1 - m2);
        Z2 += e0 + e1;
        P[4 * m + j] = cvtpk(e0, e1);
      }
    }
    Z2 += __shfl_xor(Z2, 16); Z2 += __shfl_xor(Z2, 32);
    rowscale = 1.0f / Z2;
  }

  // phase 3: ctx = P @ V. A-frag = P[4m..4m+3] (already PV layout), B = Vt.
  f32x4 o[4] = {};
  const short* vbh = Vtg + (size_t)bh * 64 * 512 + 8 * l4;
#pragma unroll
  for (int m = 0; m < 16; ++m) {
    u32x4 av;
    av[0] = P[4 * m + 0]; av[1] = P[4 * m + 1];
    av[2] = P[4 * m + 2]; av[3] = P[4 * m + 3];
    bf16x8 a = __builtin_bit_cast(bf16x8, av);
    bf16x8 b0 = *reinterpret_cast<const bf16x8*>(vbh + (size_t)(0 * 16 + l15) * 512 + m * 32);
    bf16x8 b1 = *reinterpret_cast<const bf16x8*>(vbh + (size_t)(1 * 16 + l15) * 512 + m * 32);
    bf16x8 b2 = *reinterpret_cast<const bf16x8*>(vbh + (size_t)(2 * 16 + l15) * 512 + m * 32);
    bf16x8 b3 = *reinterpret_cast<const bf16x8*>(vbh + (size_t)(3 * 16 + l15) * 512 + m * 32);
    __builtin_amdgcn_s_setprio(1);
    o[0] = __builtin_amdgcn_mfma_f32_16x16x32_bf16(a, b0, o[0], 0, 0, 0);
    o[1] = __builtin_amdgcn_mfma_f32_16x16x32_bf16(a, b1, o[1], 0, 0, 0);
    o[2] = __builtin_amdgcn_mfma_f32_16x16x32_bf16(a, b2, o[2], 0, 0, 0);
    o[3] = __builtin_amdgcn_mfma_f32_16x16x32_bf16(a, b3, o[3], 0, 0, 0);
    __builtin_amdgcn_s_setprio(0);
  }
  // C layout: lane holds ctx[q = 4*l4+r][d = ni*16+l15]; rowscale for q=Q
  // lives (post-reduce) in all lanes with l15==Q -> pull from lane 4*l4+r.
  float sc[4];
#pragma unroll
  for (int r = 0; r < 4; ++r) sc[r] = __shfl(rowscale, 4 * l4 + r);
  const int h = bh & 15;
#pragma unroll
  for (int ni = 0; ni < 4; ++ni)
#pragma unroll
    for (int r = 0; r < 4; ++r) {
      int s = qt * 64 + w * 16 + 4 * l4 + r;
      int d = ni * 16 + l15;
      ctx[((size_t)b * 512 + s) * 1024 + h * 64 + d] = f2bf(o[ni][r] * sc[r]);
    }
}

// ---------------- LayerNorm (input already h + bias + s1) -------------------
__global__ __launch_bounds__(256) void ln_kernel(
    const float* __restrict__ hbuf,
    const float* __restrict__ lw, const float* __restrict__ lb,
    float* __restrict__ out) {
  __shared__ float red[8];
  const int row = blockIdx.x, tid = threadIdx.x;
  float4 hv = reinterpret_cast<const float4*>(hbuf + (size_t)row * 1024)[tid];
  float x0 = hv.x, x1 = hv.y, x2 = hv.z, x3 = hv.w;
  float s = x0 + x1 + x2 + x3;
  float ss = x0 * x0 + x1 * x1 + x2 * x2 + x3 * x3;
  for (int o = 32; o; o >>= 1) { s += __shfl_down(s, o); ss += __shfl_down(ss, o); }
  int w = tid >> 6;
  if ((tid & 63) == 0) { red[w] = s; red[4 + w] = ss; }
  __syncthreads();
  float S = red[0] + red[1] + red[2] + red[3];
  float SS = red[4] + red[5] + red[6] + red[7];
  float u = S * (1.f / 1024.f);
  float var = SS * (1.f / 1024.f) - u * u;
  float inv = rsqrtf(var + 1e-12f);
  float4 wv = reinterpret_cast<const float4*>(lw)[tid];
  float4 bv = reinterpret_cast<const float4*>(lb)[tid];
  float4 ov;
  ov.x = wv.x * (x0 - u) * inv + bv.x;
  ov.y = wv.y * (x1 - u) * inv + bv.y;
  ov.z = wv.z * (x2 - u) * inv + bv.z;
  ov.w = wv.w * (x3 - u) * inv + bv.w;
  reinterpret_cast<float4*>(out + (size_t)row * 1024)[tid] = ov;
}

// ---------------- launcher ---------------------------------------------------
extern "C" void kernel_launch(void* const* d_in, const int* in_sizes, int n_in,
                              void* d_out, int out_size, void* d_ws, size_t ws_size,
                              hipStream_t stream) {
  const float* s1 = (const float*)d_in[0];
  const float* s2 = (const float*)d_in[1];
  const float* mask = (const float*)d_in[2];
  const float* Wq = (const float*)d_in[3]; const float* bq = (const float*)d_in[4];
  const float* Wk = (const float*)d_in[5]; const float* bk = (const float*)d_in[6];
  const float* Wv = (const float*)d_in[7]; const float* bv = (const float*)d_in[8];
  const float* Wo = (const float*)d_in[9]; const float* bo = (const float*)d_in[10];
  const float* lnw = (const float*)d_in[11]; const float* lnb = (const float*)d_in[12];
  const int* cl = (const int*)d_in[13];
  float* out = (float*)d_out;

  char* ws = (char*)d_ws;
  short* s1b = (short*)ws; ws += (size_t)4096 * 1024 * 2;
  short* s2b = (short*)ws; ws += (size_t)4096 * 1024 * 2;
  short* wqt = (short*)ws; ws += (size_t)1024 * 1024 * 2;
  short* wkt = (short*)ws; ws += (size_t)1024 * 1024 * 2;
  short* wvt = (short*)ws; ws += (size_t)1024 * 1024 * 2;
  short* wot = (short*)ws; ws += (size_t)1024 * 1024 * 2;
  short* qb  = (short*)ws; ws += (size_t)4096 * 1024 * 2;
  short* kb  = (short*)ws; ws += (size_t)4096 * 1024 * 2;
  short* vtb = (short*)ws; ws += (size_t)4096 * 1024 * 2;
  short* ctxb= (short*)ws; ws += (size_t)4096 * 1024 * 2;
  float* hb  = (float*)ws; ws += (size_t)4096 * 1024 * 4;

  prep_kernel<<<12288, 256, 0, stream>>>(s1, s1b, s2, s2b,
                                         Wq, wqt, Wk, wkt, Wv, wvt, Wo, wot);
  qkv_gemm_kernel<<<dim3(8, 32, 3), 256, 0, stream>>>(s1b, s2b, wqt, wkt, wvt,
                                                      bq, bk, bv, qb, kb, vtb);
  attn_kernel<<<dim3(8, 128), 256, 0, stream>>>(qb, kb, vtb, mask, cl, ctxb);
  wo_gemm_kernel<<<dim3(8, 32), 256, 0, stream>>>(ctxb, wot, bo, s1, hb);
  ln_kernel<<<4096, 256, 0, stream>>>(hb, lnw, lnb, out);
}

// Round 10
// 237.164 us; speedup vs baseline: 1.1897x; 1.1202x over previous
//
#include <hip/hip_runtime.h>
#include <cstdint>

#define DEV static __device__ __forceinline__

typedef __attribute__((ext_vector_type(8))) short bf16x8;   // 8 bf16 = 4 VGPRs
typedef __attribute__((ext_vector_type(4))) short bf16x4v;  // 4 bf16
typedef __attribute__((ext_vector_type(4))) float f32x4;
typedef __attribute__((ext_vector_type(4))) unsigned u32x4;

DEV float bf2f(short s) {
  union { unsigned u; float f; } c; c.u = ((unsigned)(unsigned short)s) << 16; return c.f;
}
DEV short f2bf(float f) {  // round-to-nearest-even
  union { float f; unsigned u; } c; c.f = f;
  unsigned r = c.u + 0x7FFF + ((c.u >> 16) & 1);
  return (short)(r >> 16);
}
// pack 2 f32 -> 2 bf16 in one u32 (lo = first arg), RNE. No builtin on gfx950.
DEV unsigned cvtpk(float lo, float hi) {
  unsigned r;
  asm("v_cvt_pk_bf16_f32 %0, %1, %2" : "=v"(r) : "v"(lo), "v"(hi));
  return r;
}
// async global->LDS DMA, 16B per lane (m97 pattern).
DEV void g2lds16(const void* g, void* l) {
  __builtin_amdgcn_global_load_lds(
      (const __attribute__((address_space(1))) void*)g,
      (__attribute__((address_space(3))) void*)l, 16, 0, 0);
}

// ---------------- prep: f32->bf16 convert + weight transpose, one launch ----
__global__ __launch_bounds__(256) void prep_kernel(
    const float* __restrict__ s1, short* __restrict__ s1b,
    const float* __restrict__ s2, short* __restrict__ s2b,
    const float* __restrict__ w0, short* __restrict__ t0,
    const float* __restrict__ w1, short* __restrict__ t1,
    const float* __restrict__ w2, short* __restrict__ t2,
    const float* __restrict__ w3, short* __restrict__ t3) {
  __shared__ float tile[32][33];
  const int bid = blockIdx.x, tid = threadIdx.x;
  if (bid < 8192) {
    int i = bid * 256 + tid;
    const float* in = s1; short* out = s1b;
    if (i >= 1048576) { i -= 1048576; in = s2; out = s2b; }
    float4 v = reinterpret_cast<const float4*>(in)[i];
    bf16x4v o; o[0] = f2bf(v.x); o[1] = f2bf(v.y); o[2] = f2bf(v.z); o[3] = f2bf(v.w);
    reinterpret_cast<bf16x4v*>(out)[i] = o;
  } else {
    int b2 = bid - 8192;
    int z = b2 >> 10, rem = b2 & 1023;
    int bx = rem & 31, by = rem >> 5;
    int tx = tid & 31, ty = tid >> 5;           // 32 x 8
    const float* W; short* Wt;
    switch (z) {
      case 0: W = w0; Wt = t0; break;
      case 1: W = w1; Wt = t1; break;
      case 2: W = w2; Wt = t2; break;
      default: W = w3; Wt = t3; break;
    }
#pragma unroll
    for (int j = 0; j < 4; ++j)
      tile[ty + 8 * j][tx] = W[(size_t)(by * 32 + ty + 8 * j) * 1024 + bx * 32 + tx];
    __syncthreads();
#pragma unroll
    for (int j = 0; j < 4; ++j)
      Wt[(size_t)(bx * 32 + ty + 8 * j) * 1024 + by * 32 + tx] = f2bf(tile[tx][ty + 8 * j]);
  }
}

// ---------------- shared GEMM core: m97-verified 128x128x64 structure -------
template <typename EPI>
DEV void gemm_core128(const short* __restrict__ A, const short* __restrict__ Bt,
                      int m0, int n0, EPI epi) {
  __shared__ alignas(16) short As[128 * 64];   // [m-local][k] linear (g2lds dest)
  __shared__ alignas(16) short Bs[128 * 64];   // [n-local][k] linear
  const int tid = threadIdx.x, lane = tid & 63, w = tid >> 6;
  const int wm = (w >> 1) * 64, wn = (w & 1) * 64;

  f32x4 acc[4][4] = {};

  for (int kt = 0; kt < 16; ++kt) {
    __syncthreads();   // prev iter's frag reads done
#pragma unroll
    for (int rnd = 0; rnd < 4; ++rnd) {      // A: 128 rows x 64 k
      int c = tid + rnd * 256;
      int row = c >> 3, ch = c & 7;
      g2lds16(A + (size_t)(m0 + row) * 1024 + kt * 64 + ch * 8, (char*)As + c * 16);
    }
#pragma unroll
    for (int rnd = 0; rnd < 4; ++rnd) {      // B: 128 rows x 64 k
      int c = tid + rnd * 256;
      int row = c >> 3, ch = c & 7;
      g2lds16(Bt + (size_t)(n0 + row) * 1024 + kt * 64 + ch * 8, (char*)Bs + c * 16);
    }
    asm volatile("s_waitcnt vmcnt(0)" ::: "memory");
    __syncthreads();
#pragma unroll
    for (int kk = 0; kk < 64; kk += 32) {
      bf16x8 a[4], b[4];
#pragma unroll
      for (int i = 0; i < 4; ++i)
        a[i] = *reinterpret_cast<const bf16x8*>(&As[(wm + i * 16 + (lane & 15)) * 64 + kk + 8 * (lane >> 4)]);
#pragma unroll
      for (int i = 0; i < 4; ++i)
        b[i] = *reinterpret_cast<const bf16x8*>(&Bs[(wn + i * 16 + (lane & 15)) * 64 + kk + 8 * (lane >> 4)]);
#pragma unroll
      for (int mi = 0; mi < 4; ++mi)
#pragma unroll
        for (int ni = 0; ni < 4; ++ni)
          acc[mi][ni] = __builtin_amdgcn_mfma_f32_16x16x32_bf16(a[mi], b[ni], acc[mi][ni], 0, 0, 0);
    }
  }
  // D layout (m89-verified): row = 4*(lane>>4)+r, col = lane&15
#pragma unroll
  for (int mi = 0; mi < 4; ++mi)
#pragma unroll
    for (int ni = 0; ni < 4; ++ni)
#pragma unroll
      for (int r = 0; r < 4; ++r) {
        int m = m0 + wm + mi * 16 + 4 * (lane >> 4) + r;
        int n = n0 + wn + ni * 16 + (lane & 15);
        epi(m, n, acc[mi][ni][r]);
      }
}

// merged Q/K/V projections (see R4 notes). XCD-swizzled.
__global__ __launch_bounds__(256) void qkv_gemm_kernel(
    const short* __restrict__ s1b, const short* __restrict__ s2b,
    const short* __restrict__ wqt, const short* __restrict__ wkt,
    const short* __restrict__ wvt,
    const float* __restrict__ bq, const float* __restrict__ bk,
    const float* __restrict__ bv,
    short* __restrict__ qb, short* __restrict__ kb, short* __restrict__ vtb) {
  const int z = blockIdx.z;
  int flat = blockIdx.y * 8 + blockIdx.x;       // 256 blocks/slice, %8==0
  int r8 = flat & 7, q8 = flat >> 3;
  int lg = r8 * 32 + q8;                        // XCD r8 gets lg in [32*r8, 32*r8+32)
  if (z < 2) {
    const short* A = (z == 0) ? s1b : s2b;
    const short* Bt = (z == 0) ? wqt : wkt;
    const float* bias = (z == 0) ? bq : bk;
    short* out = (z == 0) ? qb : kb;
    int n0 = (lg & 7) * 128, m0 = (lg >> 3) * 128;  // m over 4096 (seq), n over 1024
    gemm_core128(A, Bt, m0, n0, [&](int m, int n, float v) {
      v += bias[n];  // n = feature dim
      out[(((size_t)(m >> 9) * 16 + (n >> 6)) * 512 + (m & 511)) * 64 + (n & 63)] = f2bf(v);
    });
  } else {
    int m0 = (lg & 7) * 128, n0 = (lg >> 3) * 128;  // m over 1024 (d), n over 4096 (s)
    gemm_core128(wvt, s2b, m0, n0, [&](int m, int n, float v) {
      v += bv[m];    // m = feature dim (d)
      vtb[(((size_t)(n >> 9) * 16 + (m >> 6)) * 64 + (m & 63)) * 512 + (n & 511)] = f2bf(v);
    });
  }
}

// Wo projection + bias + s1 residual, f32 row-major output
__global__ __launch_bounds__(256) void wo_gemm_kernel(
    const short* __restrict__ A, const short* __restrict__ Bt,
    const float* __restrict__ bias, const float* __restrict__ s1,
    float* __restrict__ out) {
  int flat = blockIdx.y * 8 + blockIdx.x;       // 256 blocks
  int r8 = flat & 7, q8 = flat >> 3;
  int lg = r8 * 32 + q8;
  int n0 = (lg & 7) * 128, m0 = (lg >> 3) * 128;
  gemm_core128(A, Bt, m0, n0, [&](int m, int n, float v) {
    out[(size_t)m * 1024 + n] = v + bias[n] + s1[(size_t)m * 1024 + n];
  });
}

// ---------------- fused attention: LDS-staged K/V + register softmax --------
// 4 waves, 64 q-rows/block, grid (8,128) XCD-swizzled. K (phase 1) and V
// (phase 3) stream through ONE 16 KB double-buffered LDS tile [2][64x64],
// staged cooperatively via global_load_lds (coalesced, shared by all 4 waves
// -> 4x fewer loads than R7's per-wave global gathers) with 1-ahead prefetch.
// XOR swizzle (rule #21): linear LDS dest, inverse-swizzled GLOBAL source,
// swizzled ds_read: 16B chunk index c stored at c ^ (row&7) -> B-frag reads
// spread over all 8 bank-quads (the 8-cycle structural floor; unswizzled
// idles half the banks). Scores/P stay in 64 VGPRs; softmax register-only.
__global__ __launch_bounds__(256, 2) void attn_kernel(
    const short* __restrict__ Qg, const short* __restrict__ Kg,
    const short* __restrict__ Vtg, const float* __restrict__ maskg,
    const int* __restrict__ clp, short* __restrict__ ctx) {
  __shared__ alignas(16) short KV[2][64 * 64];   // 16 KB dbuf (K, then V)

  const int tid = threadIdx.x, lane = tid & 63, w = tid >> 6;
  const int l15 = lane & 15, l4 = lane >> 4;
  int flat = blockIdx.y * 8 + blockIdx.x;     // 1024 blocks
  int r8 = flat & 7, q8 = flat >> 3;
  int lg = r8 * 128 + q8;                     // XCD r8: bh in [16*r8, 16*r8+16)
  const int qt = lg & 7, bh = lg >> 3, b = bh >> 4;
  const int cl = clp[0];
  const float* mrow = maskg + b * 512;

  const char* kbh = (const char*)(Kg + (size_t)bh * 512 * 64);    // 128 B/row
  const char* vbh = (const char*)(Vtg + (size_t)bh * 64 * 512);   // 1024 B/row

  // stage one 64x64 bf16 tile (8 KB = 512 slots of 16B, 2 rounds of 256).
  // slot s -> LDS row r = s>>3, swizzled chunk cs = s&7; global chunk
  // c = cs ^ (r&7)  (involution: read applies the same XOR).
  auto stageK = [&](int t, int buf) {
#pragma unroll
    for (int rnd = 0; rnd < 2; ++rnd) {
      int s = tid + rnd * 256;
      int r = s >> 3, cs = s & 7;
      g2lds16(kbh + (size_t)(t * 64 + r) * 128 + ((cs ^ (r & 7)) * 16),
              (char*)KV[buf] + s * 16);
    }
  };
  auto stageV = [&](int t, int buf) {
#pragma unroll
    for (int rnd = 0; rnd < 2; ++rnd) {
      int s = tid + rnd * 256;
      int r = s >> 3, cs = s & 7;   // r = d, tile cols = s-range [64t,64t+64)
      g2lds16(vbh + (size_t)r * 1024 + t * 128 + ((cs ^ (r & 7)) * 16),
              (char*)KV[buf] + s * 16);
    }
  };
  // swizzled fragment read: logical (row r, 16B-chunk c)
  auto ldfrag = [&](const short* base, int r, int c) -> bf16x8 {
    return *reinterpret_cast<const bf16x8*>(base + r * 64 + ((c ^ (r & 7)) * 8));
  };

  // Q fragments straight to registers ([bh][s][64] row-major)
  const short* qbase = Qg + ((size_t)bh * 512 + qt * 64 + w * 16 + l15) * 64 + 8 * l4;
  bf16x8 qf0 = *reinterpret_cast<const bf16x8*>(qbase);
  bf16x8 qf1 = *reinterpret_cast<const bf16x8*>(qbase + 32);

  unsigned P[64];          // packed bf16 scores/probs, PV-ready layout
  float m1 = -1e30f;
  const bool odd = (l4 & 1);

  // ---- phase 1: S = K Q^T / 8 + mask, K tiles streamed through LDS --------
  stageK(0, 0);
  asm volatile("s_waitcnt vmcnt(0)" ::: "memory");
  __syncthreads();
#pragma unroll
  for (int kt = 0; kt < 8; ++kt) {
    if (kt + 1 < 8) stageK(kt + 1, (kt + 1) & 1);
    const short* kb = KV[kt & 1];
#pragma unroll
    for (int ni = 0; ni < 4; ++ni) {
      bf16x8 k0 = ldfrag(kb, ni * 16 + l15, l4);
      bf16x8 k1 = ldfrag(kb, ni * 16 + l15, 4 + l4);
      f32x4 acc = {};
      __builtin_amdgcn_s_setprio(1);
      acc = __builtin_amdgcn_mfma_f32_16x16x32_bf16(k0, qf0, acc, 0, 0, 0);
      acc = __builtin_amdgcn_mfma_f32_16x16x32_bf16(k1, qf1, acc, 0, 0, 0);
      __builtin_amdgcn_s_setprio(0);
      // C layout: lane holds k = kt*64+ni*16+4*l4+{0..3} for q-row l15
      f32x4 mk = *reinterpret_cast<const f32x4*>(&mrow[kt * 64 + ni * 16 + 4 * l4]);
      float s0 = fmaf(acc[0], 0.125f, mk[0]);
      float s1v = fmaf(acc[1], 0.125f, mk[1]);
      float s2v = fmaf(acc[2], 0.125f, mk[2]);
      float s3 = fmaf(acc[3], 0.125f, mk[3]);
      m1 = fmaxf(m1, fmaxf(fmaxf(s0, s1v), fmaxf(s2v, s3)));
      unsigned pk0 = cvtpk(s0, s1v), pk1 = cvtpk(s2v, s3);
      // exchange into PV layout: pair-swap across l4^1, then group-copy l4^2.
      unsigned e0 = __shfl_xor(pk0, 16), e1 = __shfl_xor(pk1, 16);
      unsigned h0 = odd ? e0 : pk0;
      unsigned h1 = odd ? e1 : pk1;
      unsigned h2 = odd ? pk0 : e0;
      unsigned h3 = odd ? pk1 : e1;
      unsigned g0 = __shfl_xor(h0, 32), g1 = __shfl_xor(h1, 32);
      unsigned g2 = __shfl_xor(h2, 32), g3 = __shfl_xor(h3, 32);
      bool ist = (((l4 >> 1) & 1) == (ni & 1));   // this tile feeds my k-range
      bool useh = ((l4 & 1) == (ni & 1));         // my half is in my own group
      unsigned w0 = useh ? h0 : g0;
      unsigned w1 = useh ? h1 : g1;
      unsigned w2 = useh ? h2 : g2;
      unsigned w3 = useh ? h3 : g3;
      const int mIdx = kt * 2 + (ni >> 1);
      P[4 * mIdx + 0] = ist ? w0 : P[4 * mIdx + 0];
      P[4 * mIdx + 1] = ist ? w1 : P[4 * mIdx + 1];
      P[4 * mIdx + 2] = ist ? w2 : P[4 * mIdx + 2];
      P[4 * mIdx + 3] = ist ? w3 : P[4 * mIdx + 3];
    }
    if (kt + 1 < 8) {
      asm volatile("s_waitcnt vmcnt(0)" ::: "memory");
      __syncthreads();
    }
  }

  // T14: issue V tile 0 DMA now (buf0 free: its last K readers finished at the
  // kt=6->7 barrier). The HBM/L2 latency hides under the whole softmax.
  stageV(0, 0);

  // ---- phase 2: double softmax on registers (4 l4-lanes share q-row l15) --
  m1 = fmaxf(m1, __shfl_xor(m1, 16));
  m1 = fmaxf(m1, __shfl_xor(m1, 32));
  float Z1 = 0.f;
#pragma unroll
  for (int i = 0; i < 64; ++i) {
    unsigned u = P[i];
    float lo = __uint_as_float(u << 16);
    float hi = __uint_as_float(u & 0xffff0000u);
    float e0 = __expf(lo - m1), e1 = __expf(hi - m1);
    Z1 += e0 + e1;
    P[i] = cvtpk(e0, e1);
  }
  Z1 += __shfl_xor(Z1, 16); Z1 += __shfl_xor(Z1, 32);
  float rZ1 = 1.0f / Z1;
  float rowscale = rZ1;        // P holds unnormalized e; fold 1/Z into epilogue

  if (cl) {  // softmax(1 - p + mask), p = e1*rZ1
    float m2 = -1e30f;
#pragma unroll
    for (int m = 0; m < 16; ++m) {
      f32x4 mka = *reinterpret_cast<const f32x4*>(&mrow[32 * m + 8 * l4]);
      f32x4 mkb = *reinterpret_cast<const f32x4*>(&mrow[32 * m + 8 * l4 + 4]);
#pragma unroll
      for (int j = 0; j < 4; ++j) {
        unsigned u = P[4 * m + j];
        float p0 = __uint_as_float(u << 16) * rZ1;
        float p1 = __uint_as_float(u & 0xffff0000u) * rZ1;
        float mv0 = (j < 2) ? mka[2 * j] : mkb[2 * j - 4];
        float mv1 = (j < 2) ? mka[2 * j + 1] : mkb[2 * j - 3];
        m2 = fmaxf(m2, fmaxf(1.0f - p0 + mv0, 1.0f - p1 + mv1));
      }
    }
    m2 = fmaxf(m2, __shfl_xor(m2, 16));
    m2 = fmaxf(m2, __shfl_xor(m2, 32));
    float Z2 = 0.f;
#pragma unroll
    for (int m = 0; m < 16; ++m) {
      f32x4 mka = *reinterpret_cast<const f32x4*>(&mrow[32 * m + 8 * l4]);
      f32x4 mkb = *reinterpret_cast<const f32x4*>(&mrow[32 * m + 8 * l4 + 4]);
#pragma unroll
      for (int j = 0; j < 4; ++j) {
        unsigned u = P[4 * m + j];
        float p0 = __uint_as_float(u << 16) * rZ1;
        float p1 = __uint_as_float(u & 0xffff0000u) * rZ1;
        float mv0 = (j < 2) ? mka[2 * j] : mkb[2 * j - 4];
        float mv1 = (j < 2) ? mka[2 * j + 1] : mkb[2 * j - 3];
        float e0 = __expf(1.0f - p0 + mv0 - m2);
        float e1 = __expf(1.0f - p1 + mv1 - m2);
        Z2 += e0 + e1;
        P[4 * m + j] = cvtpk(e0, e1);
      }
    }
    Z2 += __shfl_xor(Z2, 16); Z2 += __shfl_xor(Z2, 32);
    rowscale = 1.0f / Z2;
  }

  // ---- phase 3: ctx = P @ V, V tiles streamed through the same LDS dbuf ---
  asm volatile("s_waitcnt vmcnt(0)" ::: "memory");   // V tile 0 landed
  __syncthreads();
  f32x4 o[4] = {};
#pragma unroll
  for (int t = 0; t < 8; ++t) {
    if (t + 1 < 8) stageV(t + 1, (t + 1) & 1);
    const short* vb = KV[t & 1];
#pragma unroll
    for (int kk = 0; kk < 2; ++kk) {
      const int m = t * 2 + kk;
      u32x4 av;
      av[0] = P[4 * m + 0]; av[1] = P[4 * m + 1];
      av[2] = P[4 * m + 2]; av[3] = P[4 * m + 3];
      bf16x8 a = __builtin_bit_cast(bf16x8, av);
      bf16x8 b0 = ldfrag(vb, 0 * 16 + l15, kk * 4 + l4);
      bf16x8 b1 = ldfrag(vb, 1 * 16 + l15, kk * 4 + l4);
      bf16x8 b2 = ldfrag(vb, 2 * 16 + l15, kk * 4 + l4);
      bf16x8 b3 = ldfrag(vb, 3 * 16 + l15, kk * 4 + l4);
      __builtin_amdgcn_s_setprio(1);
      o[0] = __builtin_amdgcn_mfma_f32_16x16x32_bf16(a, b0, o[0], 0, 0, 0);
      o[1] = __builtin_amdgcn_mfma_f32_16x16x32_bf16(a, b1, o[1], 0, 0, 0);
      o[2] = __builtin_amdgcn_mfma_f32_16x16x32_bf16(a, b2, o[2], 0, 0, 0);
      o[3] = __builtin_amdgcn_mfma_f32_16x16x32_bf16(a, b3, o[3], 0, 0, 0);
      __builtin_amdgcn_s_setprio(0);
    }
    if (t + 1 < 8) {
      asm volatile("s_waitcnt vmcnt(0)" ::: "memory");
      __syncthreads();
    }
  }
  // C layout: lane holds ctx[q = 4*l4+r][d = ni*16+l15]; rowscale for q=Q
  // lives (post-reduce) in all lanes with l15==Q -> pull from lane 4*l4+r.
  float sc[4];
#pragma unroll
  for (int r = 0; r < 4; ++r) sc[r] = __shfl(rowscale, 4 * l4 + r);
  const int h = bh & 15;
#pragma unroll
  for (int ni = 0; ni < 4; ++ni)
#pragma unroll
    for (int r = 0; r < 4; ++r) {
      int s = qt * 64 + w * 16 + 4 * l4 + r;
      int d = ni * 16 + l15;
      ctx[((size_t)b * 512 + s) * 1024 + h * 64 + d] = f2bf(o[ni][r] * sc[r]);
    }
}

// ---------------- LayerNorm (input already h + bias + s1) -------------------
__global__ __launch_bounds__(256) void ln_kernel(
    const float* __restrict__ hbuf,
    const float* __restrict__ lw, const float* __restrict__ lb,
    float* __restrict__ out) {
  __shared__ float red[8];
  const int row = blockIdx.x, tid = threadIdx.x;
  float4 hv = reinterpret_cast<const float4*>(hbuf + (size_t)row * 1024)[tid];
  float x0 = hv.x, x1 = hv.y, x2 = hv.z, x3 = hv.w;
  float s = x0 + x1 + x2 + x3;
  float ss = x0 * x0 + x1 * x1 + x2 * x2 + x3 * x3;
  for (int o = 32; o; o >>= 1) { s += __shfl_down(s, o); ss += __shfl_down(ss, o); }
  int w = tid >> 6;
  if ((tid & 63) == 0) { red[w] = s; red[4 + w] = ss; }
  __syncthreads();
  float S = red[0] + red[1] + red[2] + red[3];
  float SS = red[4] + red[5] + red[6] + red[7];
  float u = S * (1.f / 1024.f);
  float var = SS * (1.f / 1024.f) - u * u;
  float inv = rsqrtf(var + 1e-12f);
  float4 wv = reinterpret_cast<const float4*>(lw)[tid];
  float4 bv = reinterpret_cast<const float4*>(lb)[tid];
  float4 ov;
  ov.x = wv.x * (x0 - u) * inv + bv.x;
  ov.y = wv.y * (x1 - u) * inv + bv.y;
  ov.z = wv.z * (x2 - u) * inv + bv.z;
  ov.w = wv.w * (x3 - u) * inv + bv.w;
  reinterpret_cast<float4*>(out + (size_t)row * 1024)[tid] = ov;
}

// ---------------- launcher ---------------------------------------------------
extern "C" void kernel_launch(void* const* d_in, const int* in_sizes, int n_in,
                              void* d_out, int out_size, void* d_ws, size_t ws_size,
                              hipStream_t stream) {
  const float* s1 = (const float*)d_in[0];
  const float* s2 = (const float*)d_in[1];
  const float* mask = (const float*)d_in[2];
  const float* Wq = (const float*)d_in[3]; const float* bq = (const float*)d_in[4];
  const float* Wk = (const float*)d_in[5]; const float* bk = (const float*)d_in[6];
  const float* Wv = (const float*)d_in[7]; const float* bv = (const float*)d_in[8];
  const float* Wo = (const float*)d_in[9]; const float* bo = (const float*)d_in[10];
  const float* lnw = (const float*)d_in[11]; const float* lnb = (const float*)d_in[12];
  const int* cl = (const int*)d_in[13];
  float* out = (float*)d_out;

  char* ws = (char*)d_ws;
  short* s1b = (short*)ws; ws += (size_t)4096 * 1024 * 2;
  short* s2b = (short*)ws; ws += (size_t)4096 * 1024 * 2;
  short* wqt = (short*)ws; ws += (size_t)1024 * 1024 * 2;
  short* wkt = (short*)ws; ws += (size_t)1024 * 1024 * 2;
  short* wvt = (short*)ws; ws += (size_t)1024 * 1024 * 2;
  short* wot = (short*)ws; ws += (size_t)1024 * 1024 * 2;
  short* qb  = (short*)ws; ws += (size_t)4096 * 1024 * 2;
  short* kb  = (short*)ws; ws += (size_t)4096 * 1024 * 2;
  short* vtb = (short*)ws; ws += (size_t)4096 * 1024 * 2;
  short* ctxb= (short*)ws; ws += (size_t)4096 * 1024 * 2;
  float* hb  = (float*)ws; ws += (size_t)4096 * 1024 * 4;

  prep_kernel<<<12288, 256, 0, stream>>>(s1, s1b, s2, s2b,
                                         Wq, wqt, Wk, wkt, Wv, wvt, Wo, wot);
  qkv_gemm_kernel<<<dim3(8, 32, 3), 256, 0, stream>>>(s1b, s2b, wqt, wkt, wvt,
                                                      bq, bk, bv, qb, kb, vtb);
  attn_kernel<<<dim3(8, 128), 256, 0, stream>>>(qb, kb, vtb, mask, cl, ctxb);
  wo_gemm_kernel<<<dim3(8, 32), 256, 0, stream>>>(ctxb, wot, bo, s1, hb);
  ln_kernel<<<4096, 256, 0, stream>>>(hb, lnw, lnb, out);
}